// Round 1
// baseline (135.578 us; speedup 1.0000x reference)
//
#include <hip/hip_runtime.h>

#define NEG_SLOPE 0.2f
#define EPSV 1e-16f
#define NHEADS 8
#define NCH 16
#define BKT_SHIFT 7        // 128 nodes per bucket
#define BKT_NODES 128
#define CAP 4096           // per-bucket edge capacity (mean 2048, ~45 sigma slack)
#define BIN_TPB 512
#define BIN_EPB 8192       // edges per bin block (16/thread)
#define MAX_BKT 1024

// Setup: S1[h]/D1[h] attention scalars + zero the bucket cursors.
__global__ __launch_bounds__(512) void gat_setup_kernel(
        const float* __restrict__ W1, const float* __restrict__ as1,
        const float* __restrict__ ad1, float* __restrict__ S1,
        float* __restrict__ D1, int* __restrict__ bkt_cnt, int nbuckets) {
    int t = threadIdx.x;
    for (int i = t; i < nbuckets; i += 512) bkt_cnt[i] = 0;
    if (t < NHEADS) {
        float s = 0.f, d = 0.f;
        for (int c = 0; c < NCH; ++c) {
            float w = W1[t * NCH + c];
            s += w * as1[t * NCH + c];
            d += w * ad1[t * NCH + c];
        }
        S1[t] = s;
        D1[t] = d;
    }
}

// Bin pass: LDS histogram -> local ranks; ONE global atomic per
// (block, nonempty bucket). 196 blocks (vs 391 before) halves the
// per-cursor atomic serialization; dst values retained in registers
// so pass 2 does not re-read them.
__global__ __launch_bounds__(BIN_TPB) void gat_bin_kernel(
        const int* __restrict__ ei, int E, int nbuckets,
        int* __restrict__ bkt_cnt, unsigned int* __restrict__ binned) {
    __shared__ int hist[MAX_BKT];
    __shared__ int gbase[MAX_BKT];
    int t = threadIdx.x;
    for (int i = t; i < nbuckets; i += BIN_TPB) hist[i] = 0;
    __syncthreads();
    int base = blockIdx.x * BIN_EPB;
    int dv[16];      // retained dst values (compile-time indexed -> registers)
    int lr[16];      // local ranks
#pragma unroll
    for (int k = 0; k < 4; ++k) {
        int idx = base + k * (BIN_TPB * 4) + t * 4;
        if (idx + 3 < E) {
            int4 d4 = *(const int4*)(ei + E + idx);
            dv[4 * k + 0] = d4.x; dv[4 * k + 1] = d4.y;
            dv[4 * k + 2] = d4.z; dv[4 * k + 3] = d4.w;
        } else {
#pragma unroll
            for (int u = 0; u < 4; ++u)
                dv[4 * k + u] = (idx + u < E) ? ei[E + idx + u] : -1;
        }
#pragma unroll
        for (int u = 0; u < 4; ++u)
            lr[4 * k + u] = (dv[4 * k + u] >= 0)
                ? atomicAdd(&hist[dv[4 * k + u] >> BKT_SHIFT], 1) : 0;
    }
    __syncthreads();
    for (int i = t; i < nbuckets; i += BIN_TPB) {
        int c = hist[i];
        gbase[i] = c ? (i * CAP + atomicAdd(&bkt_cnt[i], c)) : 0;
    }
    __syncthreads();
#pragma unroll
    for (int k = 0; k < 4; ++k) {
        int idx = base + k * (BIN_TPB * 4) + t * 4;
        if (idx + 3 < E) {
            int4 s4 = *(const int4*)(ei + idx);
            binned[gbase[dv[4 * k + 0] >> BKT_SHIFT] + lr[4 * k + 0]] =
                ((unsigned int)s4.x << BKT_SHIFT) | (unsigned int)(dv[4 * k + 0] & (BKT_NODES - 1));
            binned[gbase[dv[4 * k + 1] >> BKT_SHIFT] + lr[4 * k + 1]] =
                ((unsigned int)s4.y << BKT_SHIFT) | (unsigned int)(dv[4 * k + 1] & (BKT_NODES - 1));
            binned[gbase[dv[4 * k + 2] >> BKT_SHIFT] + lr[4 * k + 2]] =
                ((unsigned int)s4.z << BKT_SHIFT) | (unsigned int)(dv[4 * k + 2] & (BKT_NODES - 1));
            binned[gbase[dv[4 * k + 3] >> BKT_SHIFT] + lr[4 * k + 3]] =
                ((unsigned int)s4.w << BKT_SHIFT) | (unsigned int)(dv[4 * k + 3] & (BKT_NODES - 1));
        } else {
#pragma unroll
            for (int u = 0; u < 4; ++u)
                if (idx + u < E) {
                    unsigned int s = (unsigned int)ei[idx + u];
                    int d = dv[4 * k + u];
                    binned[gbase[d >> BKT_SHIFT] + lr[4 * k + u]] =
                        (s << BKT_SHIFT) | (unsigned int)(d & (BKT_NODES - 1));
                }
        }
    }
}

// Layer 1: per-bucket LDS counting sort (edges held in registers between
// count and scatter passes), then 2-threads-per-node register gather with
// shfl-pair combine. 782 blocks -> ~3 blocks/CU (vs 1.5 before).
__global__ __launch_bounds__(256) void gat_gather1_kernel(
        int N, const float* __restrict__ x,
        unsigned int* __restrict__ binned, const int* __restrict__ bkt_cnt,
        const float* __restrict__ S1g, const float* __restrict__ D1g,
        const float* __restrict__ W1, const float* __restrict__ b1,
        const float* __restrict__ W2, float* __restrict__ h2out,
        int* __restrict__ row_start, int* __restrict__ row_deg) {
    __shared__ unsigned int ed[CAP];          // sorted src per local node
    __shared__ int cnt[BKT_NODES];            // per-local-node degree
    __shared__ int off[BKT_NODES];            // exclusive offsets (pristine)
    __shared__ int cur[BKT_NODES];            // scatter cursors
    __shared__ float xloc[BKT_NODES];
    int b = blockIdx.x, t = threadIdx.x;
    int r = t & 1, nl = t >> 1;
    int node = (b << BKT_SHIFT) + nl;
    if (t < BKT_NODES) {
        int nn = (b << BKT_SHIFT) + t;
        xloc[t] = (nn < N) ? x[nn] : 0.f;
        cnt[t] = 0;
    }
    __syncthreads();
    int nE = bkt_cnt[b]; if (nE > CAP) nE = CAP;
    const unsigned int* bb = binned + (size_t)b * CAP;
    // pass 1: load once into registers, count local dsts
    unsigned int qa[16];
#pragma unroll
    for (int k = 0; k < 4; ++k) {
        int idx = k * 1024 + t * 4;
        if (idx + 3 < nE) {
            uint4 v4 = *(const uint4*)(bb + idx);
            qa[4 * k + 0] = v4.x; qa[4 * k + 1] = v4.y;
            qa[4 * k + 2] = v4.z; qa[4 * k + 3] = v4.w;
        } else {
#pragma unroll
            for (int u = 0; u < 4; ++u)
                qa[4 * k + u] = (idx + u < nE) ? bb[idx + u] : 0xFFFFFFFFu;
        }
#pragma unroll
        for (int u = 0; u < 4; ++u)
            if (qa[4 * k + u] != 0xFFFFFFFFu)
                atomicAdd(&cnt[qa[4 * k + u] & (BKT_NODES - 1)], 1);
    }
    __syncthreads();
    // 128-wide Hillis-Steele scan -> exclusive offsets
    int c0 = (t < BKT_NODES) ? cnt[t] : 0;
    if (t < BKT_NODES) off[t] = c0;
    __syncthreads();
    for (int o = 1; o < BKT_NODES; o <<= 1) {
        int v = (t >= o && t < BKT_NODES) ? off[t - o] : 0;
        __syncthreads();
        if (t < BKT_NODES) off[t] += v;
        __syncthreads();
    }
    if (t < BKT_NODES) {
        int oe = off[t] - c0;
        off[t] = oe;
        cur[t] = oe;
    }
    __syncthreads();
    // pass 2: scatter from registers into sorted LDS positions
#pragma unroll
    for (int k = 0; k < 4; ++k)
#pragma unroll
        for (int u = 0; u < 4; ++u) {
            unsigned int v = qa[4 * k + u];
            if (v != 0xFFFFFFFFu)
                ed[atomicAdd(&cur[v & (BKT_NODES - 1)], 1)] = v >> BKT_SHIFT;
        }
    __syncthreads();
    // write back sorted srcs for layer 2 (coalesced)
    for (int j0 = 0; j0 < nE; j0 += 1024) {
        int idx = j0 + t * 4;
        if (idx + 3 < nE) {
            *(uint4*)(binned + (size_t)b * CAP + idx) = *(const uint4*)(ed + idx);
        } else {
            for (int u = 0; u < 4; ++u)
                if (idx + u < nE) binned[(size_t)b * CAP + idx + u] = ed[idx + u];
        }
    }
    int myoff = off[nl];
    int c = cnt[nl];
    if (r == 0 && node < N) {
        row_start[node] = b * CAP + myoff;
        row_deg[node] = c;
    }
    // 2-threads-per-node register gather (thread r takes edges j % 2 == r)
    float S1[NHEADS], A[NHEADS], den[NHEADS], num[NHEADS];
    float xn = (node < N) ? xloc[nl] : 0.f;
#pragma unroll
    for (int h = 0; h < NHEADS; ++h) {
        S1[h] = S1g[h];
        A[h] = xn * D1g[h];
        float e = xn * S1[h] + A[h];          // self-loop (counted once, r==0)
        e = e > 0.f ? e : NEG_SLOPE * e;
        float ex = __expf(e);
        den[h] = r ? 0.f : ex + EPSV;
        num[h] = r ? 0.f : ex * xn;
    }
    int j = r;
    for (; j + 6 < c; j += 8) {
        unsigned int e0 = ed[myoff + j + 0], e1 = ed[myoff + j + 2];
        unsigned int e2 = ed[myoff + j + 4], e3 = ed[myoff + j + 6];
        float x0 = x[e0], x1 = x[e1], x2 = x[e2], x3 = x[e3];
#pragma unroll
        for (int h = 0; h < NHEADS; ++h) {
            float ea = x0 * S1[h] + A[h]; ea = ea > 0.f ? ea : NEG_SLOPE * ea;
            float eb = x1 * S1[h] + A[h]; eb = eb > 0.f ? eb : NEG_SLOPE * eb;
            float ec = x2 * S1[h] + A[h]; ec = ec > 0.f ? ec : NEG_SLOPE * ec;
            float ee = x3 * S1[h] + A[h]; ee = ee > 0.f ? ee : NEG_SLOPE * ee;
            float fa = __expf(ea), fb = __expf(eb), fc = __expf(ec), fd = __expf(ee);
            den[h] += (fa + fb) + (fc + fd);
            num[h] += (fa * x0 + fb * x1) + (fc * x2 + fd * x3);
        }
    }
    for (; j < c; j += 2) {
        unsigned int e0 = ed[myoff + j];
        float x0 = x[e0];
#pragma unroll
        for (int h = 0; h < NHEADS; ++h) {
            float ea = x0 * S1[h] + A[h];
            ea = ea > 0.f ? ea : NEG_SLOPE * ea;
            float fa = __expf(ea);
            den[h] += fa;
            num[h] += fa * x0;
        }
    }
    // pair combine
#pragma unroll
    for (int h = 0; h < NHEADS; ++h) {
        den[h] += __shfl_xor(den[h], 1);
        num[h] += __shfl_xor(num[h], 1);
    }
    // MLP epilogue split across the pair: r==0 heads 0..3, r==1 heads 4..7
    // (register indices stay compile-time; only memory addresses are runtime)
    float acc = 0.f;
    int hbase = r * 4;
#pragma unroll
    for (int hp = 0; hp < 4; ++hp) {
        float nh = r ? num[hp + 4] : num[hp];
        float dh = r ? den[hp + 4] : den[hp];
        float z = nh / dh;
        int kb = (hbase + hp) * NCH;
#pragma unroll
        for (int cc = 0; cc < NCH; ++cc) {
            float vv = W1[kb + cc] * z + b1[kb + cc];
            vv = vv > 0.f ? vv : (__expf(vv) - 1.f);   // elu
            acc += vv * W2[kb + cc];
        }
    }
    acc += __shfl_xor(acc, 1);
    if (r == 0 && node < N) h2out[node] = acc;
}

// Layer 2: 2-threads-per-node register gather over sorted runs.
__global__ __launch_bounds__(256) void gat_gather2_kernel(
        int N, const float* __restrict__ h2,
        const unsigned int* __restrict__ binned,
        const int* __restrict__ row_start, const int* __restrict__ row_deg,
        const float* __restrict__ as2p, const float* __restrict__ ad2p,
        const float* __restrict__ b2, float* __restrict__ out) {
    int t = threadIdx.x;
    int r = t & 1;
    int n = blockIdx.x * 128 + (t >> 1);
    if (n >= N) return;                       // pair exits together
    float a_s = as2p[0], a_d = ad2p[0];
    float hn = h2[n];
    float ad = hn * a_d;
    float e = hn * a_s + ad;                  // self-loop (counted once, r==0)
    e = e > 0.f ? e : NEG_SLOPE * e;
    float ex = __expf(e);
    float den = r ? 0.f : ex + EPSV;
    float num = r ? 0.f : ex * hn;
    int st = row_start[n], dg = row_deg[n];
    int j = r;
    for (; j + 6 < dg; j += 8) {
        unsigned int e0 = binned[st + j + 0], e1 = binned[st + j + 2];
        unsigned int e2 = binned[st + j + 4], e3 = binned[st + j + 6];
        float h0 = h2[e0], h1 = h2[e1], h3 = h2[e2], h4 = h2[e3];
        float ea = h0 * a_s + ad; ea = ea > 0.f ? ea : NEG_SLOPE * ea;
        float eb = h1 * a_s + ad; eb = eb > 0.f ? eb : NEG_SLOPE * eb;
        float ec = h3 * a_s + ad; ec = ec > 0.f ? ec : NEG_SLOPE * ec;
        float ee = h4 * a_s + ad; ee = ee > 0.f ? ee : NEG_SLOPE * ee;
        float fa = __expf(ea), fb = __expf(eb), fc = __expf(ec), fd = __expf(ee);
        den += (fa + fb) + (fc + fd);
        num += (fa * h0 + fb * h1) + (fc * h3 + fd * h4);
    }
    for (; j < dg; j += 2) {
        unsigned int e0 = binned[st + j];
        float h0 = h2[e0];
        float ea = h0 * a_s + ad;
        ea = ea > 0.f ? ea : NEG_SLOPE * ea;
        float fa = __expf(ea);
        den += fa;
        num += fa * h0;
    }
    den += __shfl_xor(den, 1);
    num += __shfl_xor(num, 1);
    if (r == 0) out[n] = num / den + b2[0];
}

extern "C" void kernel_launch(void* const* d_in, const int* in_sizes, int n_in,
                              void* d_out, int out_size, void* d_ws, size_t ws_size,
                              hipStream_t stream) {
    const float* x   = (const float*)d_in[0];
    const int*   ei  = (const int*)d_in[1];
    const float* W1  = (const float*)d_in[2];
    const float* as1 = (const float*)d_in[3];
    const float* ad1 = (const float*)d_in[4];
    const float* b1  = (const float*)d_in[5];
    const float* W2  = (const float*)d_in[6];
    const float* as2 = (const float*)d_in[7];
    const float* ad2 = (const float*)d_in[8];
    const float* b2  = (const float*)d_in[9];
    float* out = (float*)d_out;

    int N = in_sizes[0];       // 100000
    int E = in_sizes[1] / 2;   // 1600000

    int nbuckets = (N + BKT_NODES - 1) >> BKT_SHIFT;   // 782
    int nbin     = (E + BIN_EPB - 1) / BIN_EPB;        // 196
    int nb       = (N + 127) / 128;                    // 782

    // Workspace: S1[8]f | D1[8]f | h2[N]f | row_start[N]i | row_deg[N]i |
    // bkt_cnt[nbuckets]i | binned[nbuckets*CAP]u   (~14 MB of 268 MB ws)
    float* S1        = (float*)d_ws;
    float* D1        = S1 + 8;
    float* h2        = D1 + 8;
    int*   row_start = (int*)(h2 + N);
    int*   row_deg   = row_start + N;
    int*   bkt_cnt   = row_deg + N;
    unsigned int* binned = (unsigned int*)(bkt_cnt + nbuckets);

    gat_setup_kernel<<<1, 512, 0, stream>>>(W1, as1, ad1, S1, D1,
                                            bkt_cnt, nbuckets);
    gat_bin_kernel<<<nbin, BIN_TPB, 0, stream>>>(ei, E, nbuckets, bkt_cnt, binned);
    gat_gather1_kernel<<<nbuckets, 256, 0, stream>>>(N, x, binned, bkt_cnt,
                                                     S1, D1, W1, b1, W2, h2,
                                                     row_start, row_deg);
    gat_gather2_kernel<<<nb, 256, 0, stream>>>(N, h2, binned, row_start, row_deg,
                                               as2, ad2, b2, out);
}